// Round 19
// baseline (110.733 us; speedup 1.0000x reference)
//
#include <hip/hip_runtime.h>
#include <math.h>

// Adder2D: out[n,co,h,w] = -sum_{ci,kh,kw} |x[n,ci,h+kh-1,w+kw-1] - w[co,ci,kh,kw]|
// x: [16,64,32,32] f32, w: [64,64,3,3] f32, out: [16,64,32,32] f32, pad=1 stride=1.
//
// R19: R16 (best, 44.9us) + double-buffered xs, issue-early/write-late
// staging (T14), ONE barrier per round (was two). R18 falsified the pure
// ratio model (27:1 lost to 9:1). Remaining counter-visible stall: the
// 2-barrier staging convoy -- per round all 16 waves/CU drain vmcnt+lgkm,
// run the staging phase with nothing to hide the ~500cy global latency,
// and re-converge; 4 rounds of that across correlated waves ~ the missing
// 20-30%. Now per round: issue next-round global loads FIRST (3 guarded
// dwordx4, held in regs), compute current buffer's 4 ci (~2.3k cy hides
// the latency), sched_barrier(0), ds-write staged data to the other
// buffer, single __syncthreads(). Round r+1's writes to buf[r&1] are
// separated from round r's reads by that barrier -- correct with one
// barrier. All else identical to R16: CG=8 co/thread, 2px, 4 cig groups,
// LW=35 conflict-free layout, octet w s_load (WSLICE=128), f2 core,
// aliased LDS reduction. Grid (4,8,16)=512 x 512thr, 2 blocks/CU.

#define N_   16
#define CI_  64
#define CO_  64
#define HW_  32
#define CG   8      // co per thread (= all of COB)
#define COB  8      // co per block
#define RG   8      // pixel rows per block
#define CIC  16     // ci planes staged per round
#define CPG  4      // ci planes computed per group per round
#define ROWS (RG + 2)
#define LW   35     // word0 = left halo, 1..32 = data, 33 = right halo, 34 pad
#define WSLICE 128  // floats per (co-octet,ci) w slot (72 used, 512B aligned)

#define XS_WORDS (CIC * ROWS * LW)        // 5600 words = 22400 B per buffer
#define RED_WORDS (3 * 128 * 16)          // 6144 words, aliases the buffers

typedef __attribute__((ext_vector_type(2))) float f2;

// ---- repack: w[co][ci][t] -> wr[(co/8)*64+ci][ (co&7)*9 + t ], 128-f slots ----
__global__ void repack_w(const float* __restrict__ w, float* __restrict__ wr)
{
    int i  = blockIdx.x * 256 + threadIdx.x;   // 4096 = (co,ci) pairs
    int co = i >> 6;
    int ci = i & 63;
    float* dst = wr + (size_t)((co >> 3) * 64 + ci) * WSLICE + (co & 7) * 9;
    const float* src = w + (size_t)co * (CI_ * 9) + ci * 9;
#pragma unroll
    for (int t = 0; t < 9; ++t) dst[t] = src[t];
}

__global__ __launch_bounds__(512, 4) void adder2d_kernel(
    const float* __restrict__ x, const float* __restrict__ wr,
    float* __restrict__ out)
{
    __shared__ __align__(16) float smem[2 * XS_WORDS];   // 44800 B
    float (*red)[128][16] = (float (*)[128][16])smem;    // epilogue alias

    const int tid = threadIdx.x;
    const int u   = tid & 15;            // col-pair: pixels at cols 2u, 2u+1
    const int rl  = (tid >> 4) & 7;      // pixel row within block
    const int cig = tid >> 7;            // ci group: 0..3 (uniform per wave)
    const int r0  = blockIdx.x * RG;
    const int co0 = blockIdx.y * COB;
    const int n   = blockIdx.z;

    const int cigs = __builtin_amdgcn_readfirstlane(cig);
    const float* wrb = wr + (size_t)blockIdx.y * 64 * WSLICE;

    // ---- zero both buffers once: halo words + OOB row slots stay zero
    //      forever (never written by staging); data slots overwritten ----
    for (int i = tid; i < 2 * XS_WORDS / 4; i += 512)
        ((float4*)smem)[i] = float4{0.f, 0.f, 0.f, 0.f};

    f2 acc2[CG];                         // .x = col 2u, .y = col 2u+1
#pragma unroll
    for (int j = 0; j < CG; ++j) acc2[j] = f2{0.f, 0.f};

    const float* xn = x + (size_t)n * CI_ * HW_ * HW_;
    const int pbase = cig * CPG;

    // staging decomposition: 1280 float4 units, 2.5/thread -> 3 guarded slots
    const int i0 = tid, i1 = tid + 512, i2 = tid + 1024;   // i2 only tid<256

#define SIDX(I, PLANE, RR, F4, GR)                                            \
    const int PLANE = (I) / (ROWS * 8);                                       \
    const int RR    = ((I) - PLANE * (ROWS * 8)) >> 3;                        \
    const int F4    = (I) & 7;                                                \
    const int GR    = r0 - 1 + RR;

    // ---- prologue: stage round 0 into buffer 0 ----
    {
        for (int i = tid; i < CIC * ROWS * 8; i += 512) {
            SIDX(i, plane, rr, f4, gr)
            if ((unsigned)gr < HW_) {
                float4 v = ((const float4*)(xn + (size_t)plane * HW_ * HW_
                                            + gr * HW_))[f4];
                float* dst = smem + (plane * ROWS + rr) * LW + 1 + 4 * f4;
                dst[0] = v.x; dst[1] = v.y; dst[2] = v.z; dst[3] = v.w;
            }
        }
    }
    __syncthreads();

#pragma unroll 1
    for (int round = 0; round < CI_ / CIC; ++round) {
        const int cur = round & 1;
        const float* xsc = smem + cur * XS_WORDS;
        const int cc0  = round * CIC;
        const int cc0n = cc0 + CIC;
        const bool more = (round < CI_ / CIC - 1);

        // ---- issue next round's loads EARLY (held in regs thru compute) ----
        float4 L0, L1, L2;
        bool v0 = false, v1 = false, v2 = false;
        if (more) {
            { SIDX(i0, p, rr, f4, gr)
              if ((unsigned)gr < HW_) { v0 = true;
                  L0 = ((const float4*)(xn + (size_t)(cc0n + p) * HW_ * HW_ + gr * HW_))[f4]; } }
            { SIDX(i1, p, rr, f4, gr)
              if ((unsigned)gr < HW_) { v1 = true;
                  L1 = ((const float4*)(xn + (size_t)(cc0n + p) * HW_ * HW_ + gr * HW_))[f4]; } }
            if (tid < 256) { SIDX(i2, p, rr, f4, gr)
              if ((unsigned)gr < HW_) { v2 = true;
                  L2 = ((const float4*)(xn + (size_t)(cc0n + p) * HW_ * HW_ + gr * HW_))[f4]; } }
        }

        // ---- compute current buffer: 4 ci per thread ----
#pragma unroll
        for (int cil = 0; cil < CPG; ++cil) {
            const int pl  = pbase + cil;
            const int cis = cc0 + cigs * CPG + cil;

            const float* wu_p = wrb + (size_t)cis * WSLICE;
            float wu[72];
#pragma unroll
            for (int t = 0; t < 72; ++t) wu[t] = wu_p[t];

            f2 xp[3][3];
#pragma unroll
            for (int kh = 0; kh < 3; ++kh) {
                const float* row = xsc + (pl * ROWS + rl + kh) * LW + 2 * u;
                float a = row[0], b = row[1], c = row[2], d = row[3];
                xp[kh][0] = f2{a, b}; xp[kh][1] = f2{b, c}; xp[kh][2] = f2{c, d};
            }

#pragma unroll
            for (int kh = 0; kh < 3; ++kh)
#pragma unroll
                for (int kw = 0; kw < 3; ++kw) {
#pragma unroll
                    for (int j = 0; j < CG; ++j) {
                        const float wjt = wu[j * 9 + kh * 3 + kw];
                        f2 dv = xp[kh][kw] - f2{wjt, wjt};
                        acc2[j] += __builtin_elementwise_abs(dv);
                    }
                }
        }

        // ---- write-late: staged data -> other buffer, then ONE barrier ----
        __builtin_amdgcn_sched_barrier(0);
        if (more) {
            float* xsn = smem + (cur ^ 1) * XS_WORDS;
            if (v0) { SIDX(i0, p, rr, f4, gr) (void)gr;
                float* d = xsn + (p * ROWS + rr) * LW + 1 + 4 * f4;
                d[0] = L0.x; d[1] = L0.y; d[2] = L0.z; d[3] = L0.w; }
            if (v1) { SIDX(i1, p, rr, f4, gr) (void)gr;
                float* d = xsn + (p * ROWS + rr) * LW + 1 + 4 * f4;
                d[0] = L1.x; d[1] = L1.y; d[2] = L1.z; d[3] = L1.w; }
            if (v2) { SIDX(i2, p, rr, f4, gr) (void)gr;
                float* d = xsn + (p * ROWS + rr) * LW + 1 + 4 * f4;
                d[0] = L2.x; d[1] = L2.y; d[2] = L2.z; d[3] = L2.w; }
        }
        __syncthreads();
    }
#undef SIDX

    // ---- combine the four ci-group partials (red aliases dead buffers) ----
    if (cig != 0) {
        int t = tid & 127;
#pragma unroll
        for (int j = 0; j < CG; j += 2)
            *(float4*)&red[cig - 1][t][2 * j] =
                float4{acc2[j].x, acc2[j].y, acc2[j + 1].x, acc2[j + 1].y};
    }
    __syncthreads();
    if (cig == 0) {
#pragma unroll
        for (int g = 0; g < 3; ++g)
#pragma unroll
            for (int j = 0; j < CG; j += 2) {
                float4 rv = *(const float4*)&red[g][tid][2 * j];
                acc2[j].x     += rv.x; acc2[j].y     += rv.y;
                acc2[j + 1].x += rv.z; acc2[j + 1].y += rv.w;
            }
        float* op = out + (((size_t)n * CO_ + co0) * HW_ + (r0 + rl)) * HW_ + 2 * u;
#pragma unroll
        for (int j = 0; j < CG; ++j)
            *(float2*)&op[(size_t)j * HW_ * HW_] = float2{-acc2[j].x, -acc2[j].y};
    }
}

extern "C" void kernel_launch(void* const* d_in, const int* in_sizes, int n_in,
                              void* d_out, int out_size, void* d_ws, size_t ws_size,
                              hipStream_t stream) {
    const float* x  = (const float*)d_in[0];
    const float* wp = (const float*)d_in[1];
    float* out      = (float*)d_out;
    float* wr       = (float*)d_ws;   // 256 KiB (proven-safe footprint)

    repack_w<<<dim3(16), 256, 0, stream>>>(wp, wr);
    dim3 grid(HW_ / RG, CO_ / COB, N_);   // (4, 8, 16) = 512 blocks
    adder2d_kernel<<<grid, 512, 0, stream>>>(x, wr, out);
}

// Round 20
// 96.485 us; speedup vs baseline: 1.1477x; 1.1477x over previous
//
#include <hip/hip_runtime.h>
#include <math.h>

// Adder2D: out[n,co,h,w] = -sum_{ci,kh,kw} |x[n,ci,h+kh-1,w+kw-1] - w[co,ci,kh,kw]|
// x: [16,64,32,32] f32, w: [64,64,3,3] f32, out: [16,64,32,32] f32, pad=1 stride=1.
//
// FINAL (revert to R16, session best: 44.9us dispatch). R19's T14 staging
// overlap regressed 28us (live-range stretch + undrainable vmcnt at the
// write phase). Across 13 measured variants the only reproducible win was
// R16's core:overhead ratio lever (CG=8, 9:1); occupancy, w-feed path,
// bank conflicts, latency pipelining (R17, fully materialized), VOP3P
// packing, 27:1 ratio (R18) and staging overlap (R19) were all null or
// negative. No counter shows a saturated pipe; the residual stall is
// below counter granularity. R16 verbatim:
//   - 512 thr = 128 out-threads x 4 cig groups, COB=8, grid (4,8,16)
//   - LW=35 odd-stride LDS layout (conflict-free reads+writes)
//   - w via readfirstlane-uniform s_load octet slices (WSLICE=128)
//   - f2 packed core (pk_sub + 2x abs-add), 216 VALU per 12 LDS reads

#define N_   16
#define CI_  64
#define CO_  64
#define HW_  32
#define CG   8      // co per thread (= all of COB)
#define COB  8      // co per block
#define RG   8      // pixel rows per block
#define CIC  16     // ci planes staged per round
#define CPG  4      // ci planes computed per group per round
#define ROWS (RG + 2)
#define LW   35     // word0 = left halo, 1..32 = data, 33 = right halo, 34 pad
#define WSLICE 128  // floats per (co-octet,ci) w slot (72 used, 512B aligned)

#define XS_WORDS (CIC * ROWS * LW)        // 5600 words = 22400 B
#define RED_WORDS (3 * 128 * 16)          // 6144 words = 24576 B
#define SMEM_WORDS (RED_WORDS > XS_WORDS ? RED_WORDS : XS_WORDS)

typedef __attribute__((ext_vector_type(2))) float f2;

// ---- repack: w[co][ci][t] -> wr[(co/8)*64+ci][ (co&7)*9 + t ], 128-f slots ----
__global__ void repack_w(const float* __restrict__ w, float* __restrict__ wr)
{
    int i  = blockIdx.x * 256 + threadIdx.x;   // 4096 = (co,ci) pairs
    int co = i >> 6;
    int ci = i & 63;
    float* dst = wr + (size_t)((co >> 3) * 64 + ci) * WSLICE + (co & 7) * 9;
    const float* src = w + (size_t)co * (CI_ * 9) + ci * 9;
#pragma unroll
    for (int t = 0; t < 9; ++t) dst[t] = src[t];
}

__global__ __launch_bounds__(512, 4) void adder2d_kernel(
    const float* __restrict__ x, const float* __restrict__ wr,
    float* __restrict__ out)
{
    __shared__ __align__(16) float smem[SMEM_WORDS];
    float (*xs)[ROWS][LW] = (float (*)[ROWS][LW])smem;   // phase A
    float (*red)[128][16] = (float (*)[128][16])smem;    // phase B: aliases xs

    const int tid = threadIdx.x;
    const int u   = tid & 15;            // col-pair: pixels at cols 2u, 2u+1
    const int rl  = (tid >> 4) & 7;      // pixel row within block
    const int cig = tid >> 7;            // ci group: 0..3 (uniform per wave)
    const int r0  = blockIdx.x * RG;
    const int co0 = blockIdx.y * COB;
    const int n   = blockIdx.z;

    // wave-uniform group index -> provably scalar w pointer (s_load path)
    const int cigs = __builtin_amdgcn_readfirstlane(cig);
    const float* wrb = wr + (size_t)blockIdx.y * 64 * WSLICE;

    // ---- zero xs once: halo words (0,33) and OOB row slots stay zero ----
    for (int i = tid; i < XS_WORDS / 4; i += 512)
        ((float4*)smem)[i] = float4{0.f, 0.f, 0.f, 0.f};

    f2 acc2[CG];                         // .x = pixel col 2u, .y = col 2u+1
#pragma unroll
    for (int j = 0; j < CG; ++j) acc2[j] = f2{0.f, 0.f};

    const float* xn = x + (size_t)n * CI_ * HW_ * HW_;
    const int pbase = cig * CPG;

    for (int round = 0; round < CI_ / CIC; ++round) {
        const int cc0 = round * CIC;
        __syncthreads();   // protect LDS from previous round's readers
        // ---- stage CIC planes, rows r0-1..r0+8: 1280 float4 units ----
        for (int i = tid; i < CIC * ROWS * (HW_ / 4); i += 512) {
            int plane = i / (ROWS * (HW_ / 4));
            int rem   = i - plane * (ROWS * (HW_ / 4));
            int rr    = rem >> 3;
            int f4    = rem & 7;
            int gr    = r0 - 1 + rr;
            if ((unsigned)gr < HW_) {
                float4 v = ((const float4*)(xn + (size_t)(cc0 + plane) * HW_ * HW_
                                            + gr * HW_))[f4];
                float* dst = &xs[plane][rr][1 + 4 * f4];   // data words 1..32
                dst[0] = v.x; dst[1] = v.y; dst[2] = v.z; dst[3] = v.w;
            }
        }
        __syncthreads();

#pragma unroll 1
        for (int cil = 0; cil < CPG; ++cil) {
            const int pl  = pbase + cil;             // per-thread (LDS path)
            const int cis = cc0 + cigs * CPG + cil;  // uniform (SMEM path)

            // ---- w octet-slice (72 floats) from uniform ptr -> s_load ----
            const float* wu_p = wrb + (size_t)cis * WSLICE;
            float wu[72];
#pragma unroll
            for (int t = 0; t < 72; ++t) wu[t] = wu_p[t];

            // x window: 3 overlapping f2 pairs per row, 12 b32 reads,
            // reused by all 8 co (the amortization)
            f2 xp[3][3];
#pragma unroll
            for (int kh = 0; kh < 3; ++kh) {
                const float* row = &xs[pl][rl + kh][2 * u];
                float a = row[0], b = row[1], c = row[2], d = row[3];
                xp[kh][0] = f2{a, b};
                xp[kh][1] = f2{b, c};
                xp[kh][2] = f2{c, d};
            }

            // packed core: 9 taps x 8 co x {pk_sub, 2x abs-add} = 216 VALU
#pragma unroll
            for (int kh = 0; kh < 3; ++kh)
#pragma unroll
                for (int kw = 0; kw < 3; ++kw) {
                    const int t = kh * 3 + kw;
#pragma unroll
                    for (int j = 0; j < CG; ++j) {
                        const float wjt = wu[j * 9 + t];
                        f2 dv = xp[kh][kw] - f2{wjt, wjt};
                        acc2[j] += __builtin_elementwise_abs(dv);
                    }
                }
        }
    }

    // ---- combine the four ci-group partials (red aliases dead xs) ----
    __syncthreads();   // all xs readers done before overwrite
    if (cig != 0) {
        int t = tid & 127;
#pragma unroll
        for (int j = 0; j < CG; j += 2)
            *(float4*)&red[cig - 1][t][2 * j] =
                float4{acc2[j].x, acc2[j].y, acc2[j + 1].x, acc2[j + 1].y};
    }
    __syncthreads();
    if (cig == 0) {
#pragma unroll
        for (int g = 0; g < 3; ++g)
#pragma unroll
            for (int j = 0; j < CG; j += 2) {
                float4 rv = *(const float4*)&red[g][tid][2 * j];
                acc2[j].x     += rv.x; acc2[j].y     += rv.y;
                acc2[j + 1].x += rv.z; acc2[j + 1].y += rv.w;
            }
        float* op = out + (((size_t)n * CO_ + co0) * HW_ + (r0 + rl)) * HW_ + 2 * u;
#pragma unroll
        for (int j = 0; j < CG; ++j)
            *(float2*)&op[(size_t)j * HW_ * HW_] = float2{-acc2[j].x, -acc2[j].y};
    }
}

extern "C" void kernel_launch(void* const* d_in, const int* in_sizes, int n_in,
                              void* d_out, int out_size, void* d_ws, size_t ws_size,
                              hipStream_t stream) {
    const float* x  = (const float*)d_in[0];
    const float* wp = (const float*)d_in[1];
    float* out      = (float*)d_out;
    float* wr       = (float*)d_ws;   // 256 KiB (proven-safe footprint)

    repack_w<<<dim3(16), 256, 0, stream>>>(wp, wr);
    dim3 grid(HW_ / RG, CO_ / COB, N_);   // (4, 8, 16) = 512 blocks
    adder2d_kernel<<<grid, 512, 0, stream>>>(x, wr, out);
}

// Round 22
// 96.416 us; speedup vs baseline: 1.1485x; 1.0007x over previous
//
#include <hip/hip_runtime.h>
#include <math.h>

// Adder2D: out[n,co,h,w] = -sum_{ci,kh,kw} |x[n,ci,h+kh-1,w+kw-1] - w[co,ci,kh,kw]|
// x: [16,64,32,32] f32, w: [64,64,3,3] f32, out: [16,64,32,32] f32, pad=1 stride=1.
//
// R21-retry: previous submission died at container level (same infra
// signature as R6/R10 first attempts; both passed on identical resubmit).
// Source audited: LDS indices bounded (max plane 15 / row 9 / col 33 in
// [16][10][35]), SMEM 6144 words covers both phases, global accesses
// guarded, barriers uniform. Resubmitted unchanged.
//
// R21: minimum-instruction-stream test. Unresolved contradiction: derived
// VALUBusy ~67% -- real, or 2x gfx94x-inflated? R14's audit said emitted
// VALU must be 1.5-2x the source model; R16's source contains exactly that
// bloat: (a) f2 packed core needs SGPR-w splats to VGPR pairs and 2x v_and
// for |.| (no packed abs modifier) -> packing is at best parity (explains
// R15 null); (b) '#pragma unroll 1' on cil makes pl runtime -> per-ci LDS
// address arithmetic instead of offset: immediates. This kernel removes
// every identified source of non-core VALU:
//   - scalar core: v_sub_f32 (SGPR w direct, no splat) + v_add_f32 abs
//     = exactly 2 instr/elem, 288/ci for CG=8
//   - cil fully unrolled: pl compile-time -> one LDS base, 48 ds_read
//     with offset: immediates, zero per-ci address VALU
//   - window as 4 scalar b32 reads/row (R11-style, 147K-conflict class)
// If VALUBusy is real: dur 36-41us. If inflated (true ~31%): flat 44-48
// -> plateau declared next round. Structure otherwise = R16 (512 thr,
// 4 cig groups, COB=8, CIC=16, LW=35, octet w s_load, aliased reduction).

#define N_   16
#define CI_  64
#define CO_  64
#define HW_  32
#define CG   8      // co per thread (= all of COB)
#define COB  8      // co per block
#define RG   8      // pixel rows per block
#define CIC  16     // ci planes staged per round
#define CPG  4      // ci planes computed per group per round
#define ROWS (RG + 2)
#define LW   35     // word0 = left halo, 1..32 = data, 33 = right halo, 34 pad
#define WSLICE 128  // floats per (co-octet,ci) w slot (72 used, 512B aligned)

#define XS_WORDS (CIC * ROWS * LW)        // 5600 words = 22400 B
#define RED_WORDS (3 * 128 * 16)          // 6144 words = 24576 B
#define SMEM_WORDS (RED_WORDS > XS_WORDS ? RED_WORDS : XS_WORDS)

// ---- repack: w[co][ci][t] -> wr[(co/8)*64+ci][ (co&7)*9 + t ], 128-f slots ----
__global__ void repack_w(const float* __restrict__ w, float* __restrict__ wr)
{
    int i  = blockIdx.x * 256 + threadIdx.x;   // 4096 = (co,ci) pairs
    int co = i >> 6;
    int ci = i & 63;
    float* dst = wr + (size_t)((co >> 3) * 64 + ci) * WSLICE + (co & 7) * 9;
    const float* src = w + (size_t)co * (CI_ * 9) + ci * 9;
#pragma unroll
    for (int t = 0; t < 9; ++t) dst[t] = src[t];
}

__global__ __launch_bounds__(512, 4) void adder2d_kernel(
    const float* __restrict__ x, const float* __restrict__ wr,
    float* __restrict__ out)
{
    __shared__ __align__(16) float smem[SMEM_WORDS];
    float (*xs)[ROWS][LW] = (float (*)[ROWS][LW])smem;   // phase A
    float (*red)[128][16] = (float (*)[128][16])smem;    // phase B: aliases xs

    const int tid = threadIdx.x;
    const int u   = tid & 15;            // col-pair: pixels at cols 2u, 2u+1
    const int rl  = (tid >> 4) & 7;      // pixel row within block
    const int cig = tid >> 7;            // ci group: 0..3 (uniform per wave)
    const int r0  = blockIdx.x * RG;
    const int co0 = blockIdx.y * COB;
    const int n   = blockIdx.z;

    // wave-uniform group index -> provably scalar w pointer (s_load path)
    const int cigs = __builtin_amdgcn_readfirstlane(cig);
    const float* wrb = wr + (size_t)blockIdx.y * 64 * WSLICE;

    // ---- zero xs once: halo words (0,33) and OOB row slots stay zero ----
    for (int i = tid; i < XS_WORDS / 4; i += 512)
        ((float4*)smem)[i] = float4{0.f, 0.f, 0.f, 0.f};

    float acc0[CG], acc1[CG];            // col 2u / col 2u+1
#pragma unroll
    for (int j = 0; j < CG; ++j) { acc0[j] = 0.f; acc1[j] = 0.f; }

    const float* xn = x + (size_t)n * CI_ * HW_ * HW_;
    const int pbase = cig * CPG;

    // single LDS base for the whole kernel: &xs[pbase][rl][2u]; the
    // fully-unrolled cil/kh structure makes every read offset a
    // compile-time immediate from here.
    const float* xbase = &xs[pbase][rl][2 * u];

    for (int round = 0; round < CI_ / CIC; ++round) {
        const int cc0 = round * CIC;
        __syncthreads();   // protect LDS from previous round's readers
        // ---- stage CIC planes, rows r0-1..r0+8: 1280 float4 units ----
        for (int i = tid; i < CIC * ROWS * (HW_ / 4); i += 512) {
            int plane = i / (ROWS * (HW_ / 4));
            int rem   = i - plane * (ROWS * (HW_ / 4));
            int rr    = rem >> 3;
            int f4    = rem & 7;
            int gr    = r0 - 1 + rr;
            if ((unsigned)gr < HW_) {
                float4 v = ((const float4*)(xn + (size_t)(cc0 + plane) * HW_ * HW_
                                            + gr * HW_))[f4];
                float* dst = &xs[plane][rr][1 + 4 * f4];   // data words 1..32
                dst[0] = v.x; dst[1] = v.y; dst[2] = v.z; dst[3] = v.w;
            }
        }
        __syncthreads();

#pragma unroll
        for (int cil = 0; cil < CPG; ++cil) {            // FULLY UNROLLED
            const int cis = cc0 + cigs * CPG + cil;      // uniform (SMEM path)

            // ---- w octet-slice (72 floats) from uniform ptr -> s_load ----
            const float* wu_p = wrb + (size_t)cis * WSLICE;
            float wu[72];
#pragma unroll
            for (int t = 0; t < 72; ++t) wu[t] = wu_p[t];

            // window: 12 scalar b32 reads, all offsets compile-time
            // (cil*ROWS*LW + kh*LW + c), conflict-free at odd LW
            float xw[3][4];
#pragma unroll
            for (int kh = 0; kh < 3; ++kh)
#pragma unroll
                for (int c = 0; c < 4; ++c)
                    xw[kh][c] = xbase[cil * (ROWS * LW) + kh * LW + c];

            // scalar core: 9 taps x 8 co x 2 px x {v_sub(s-operand),
            // v_add(abs)} = 288 VALU, zero splats, zero addr arith
#pragma unroll
            for (int kh = 0; kh < 3; ++kh)
#pragma unroll
                for (int kw = 0; kw < 3; ++kw) {
                    const int t = kh * 3 + kw;
                    const float xa = xw[kh][kw];
                    const float xb = xw[kh][kw + 1];
#pragma unroll
                    for (int j = 0; j < CG; ++j) {
                        const float wjt = wu[j * 9 + t];
                        acc0[j] += fabsf(xa - wjt);
                        acc1[j] += fabsf(xb - wjt);
                    }
                }
        }
    }

    // ---- combine the four ci-group partials (red aliases dead xs) ----
    __syncthreads();   // all xs readers done before overwrite
    if (cig != 0) {
        int t = tid & 127;
#pragma unroll
        for (int j = 0; j < CG; j += 2)
            *(float4*)&red[cig - 1][t][2 * j] =
                float4{acc0[j], acc1[j], acc0[j + 1], acc1[j + 1]};
    }
    __syncthreads();
    if (cig == 0) {
#pragma unroll
        for (int g = 0; g < 3; ++g)
#pragma unroll
            for (int j = 0; j < CG; j += 2) {
                float4 rv = *(const float4*)&red[g][tid][2 * j];
                acc0[j]     += rv.x; acc1[j]     += rv.y;
                acc0[j + 1] += rv.z; acc1[j + 1] += rv.w;
            }
        float* op = out + (((size_t)n * CO_ + co0) * HW_ + (r0 + rl)) * HW_ + 2 * u;
#pragma unroll
        for (int j = 0; j < CG; ++j)
            *(float2*)&op[(size_t)j * HW_ * HW_] = float2{-acc0[j], -acc1[j]};
    }
}

extern "C" void kernel_launch(void* const* d_in, const int* in_sizes, int n_in,
                              void* d_out, int out_size, void* d_ws, size_t ws_size,
                              hipStream_t stream) {
    const float* x  = (const float*)d_in[0];
    const float* wp = (const float*)d_in[1];
    float* out      = (float*)d_out;
    float* wr       = (float*)d_ws;   // 256 KiB (proven-safe footprint)

    repack_w<<<dim3(16), 256, 0, stream>>>(wp, wr);
    dim3 grid(HW_ / RG, CO_ / COB, N_);   // (4, 8, 16) = 512 blocks
    adder2d_kernel<<<grid, 512, 0, stream>>>(x, wr, out);
}